// Round 1
// baseline (485.367 us; speedup 1.0000x reference)
//
#include <hip/hip_runtime.h>

typedef __bf16 bf16x8 __attribute__((ext_vector_type(8)));
typedef __bf16 bf16x4 __attribute__((ext_vector_type(4)));
typedef float  f32x4  __attribute__((ext_vector_type(4)));

static constexpr int kS = 8192;
static constexpr int kD = 128;
static constexpr int kRowsPerTensor = 2 * 16 * kS;            // 262144
static constexpr int kFragElems = 128 * 128;                  // 16384 bf16 per matrix

// ---------------------------------------------------------------------------
// Kernel 1: build Householder product Q, column-parallel (one wave per column).
// Column j evolves independently: w_j = v . Q[:,j]; Q[:,j] -= c * w_j * v.
// Emits Q^T and Q in bf16, pre-swizzled into MFMA B-fragment order:
//   frag idx for element (k, n) = ((kstep*8 + ntile)*64 + quad*16 + (n&15))*8 + (k&7)
//   with kstep = k>>5, quad = (k>>3)&3, ntile = n>>4.
// ---------------------------------------------------------------------------
__global__ __launch_bounds__(1024) void rnrope_build_q(
    const float* __restrict__ vs,
    __bf16* __restrict__ wsQT,   // B-operand for GEMM1: B1[k][n] = Q[n][k]
    __bf16* __restrict__ wsQ) {  // B-operand for GEMM2: B2[k][n] = Q[k][n]
  __shared__ float vsh[64 * 128];
  const int tid = threadIdx.x;
  for (int i = tid; i < 2048; i += 1024)
    ((float4*)vsh)[i] = ((const float4*)vs)[i];
  __syncthreads();

  const int col  = blockIdx.x * 16 + (tid >> 6);  // 0..127 (grid = 8 blocks)
  const int lane = tid & 63;

  float qlo = (col == lane)      ? 1.0f : 0.0f;   // Q[lane][col]
  float qhi = (col == lane + 64) ? 1.0f : 0.0f;   // Q[lane+64][col]

  for (int r = 0; r < 64; ++r) {
    float vlo = vsh[r * 128 + lane];
    float vhi = vsh[r * 128 + lane + 64];
    float t0 = vlo * qlo + vhi * qhi;   // partial v . q_col
    float t1 = vlo * vlo + vhi * vhi;   // partial v . v
    #pragma unroll
    for (int off = 32; off > 0; off >>= 1) {
      t0 += __shfl_xor(t0, off);
      t1 += __shfl_xor(t1, off);
    }
    float cf = 2.0f / (t1 + 1e-8f);
    float sf = cf * t0;
    qlo -= sf * vlo;
    qhi -= sf * vhi;
  }

  // Q^T frags: element (k=col, n=i), i = lane, lane+64
  {
    const int ks = col >> 5, qd = (col >> 3) & 3, jj = col & 7;
    #pragma unroll
    for (int h = 0; h < 2; ++h) {
      int i = lane + h * 64;
      float val = h ? qhi : qlo;
      int nt = i >> 4;
      int lp = qd * 16 + (i & 15);
      wsQT[((ks * 8 + nt) * 64 + lp) * 8 + jj] = (__bf16)val;
    }
  }
  // Q frags: element (k=i, n=col)
  {
    const int nt = col >> 4;
    const int nn = col & 15;
    #pragma unroll
    for (int h = 0; h < 2; ++h) {
      int i = lane + h * 64;
      float val = h ? qhi : qlo;
      int ks = i >> 5, qd = (i >> 3) & 3, jj = i & 7;
      wsQ[((ks * 8 + nt) * 64 + qd * 16 + nn) * 8 + jj] = (__bf16)val;
    }
  }
}

// ---------------------------------------------------------------------------
// Kernel 2: per 128-row tile: Y = X @ Q^T (MFMA), RoPE in-register,
// LDS round-trip (C-layout -> A-layout), Z = Yrot @ Q (MFMA), store f32.
// LDS: 32 KiB B-slot (QT frags, then Q frags) + 32 KiB A-slot (X, then Yrot).
// ---------------------------------------------------------------------------
__global__ __launch_bounds__(512, 4) void rnrope_main(
    const float* __restrict__ qg, const float* __restrict__ kg,
    const float* __restrict__ cosg, const float* __restrict__ sing,
    const __bf16* __restrict__ wsQT, const __bf16* __restrict__ wsQ,
    float* __restrict__ outg) {
  __shared__ __align__(16) __bf16 ldsB[kFragElems];
  __shared__ __align__(16) __bf16 ldsA[kFragElems];

  const int tid    = threadIdx.x;
  const int blk    = blockIdx.x;          // 0..4095
  const int tensor = blk >> 11;           // 0 = q, 1 = k
  const int tile   = blk & 2047;
  const float* __restrict__ Xg = tensor ? kg : qg;
  float* __restrict__ Og = outg + (size_t)tensor * (size_t)kRowsPerTensor * kD;
  const int row0 = tile * 128;

  // stage Q^T frags into B-slot (already frag-ordered in ws)
  #pragma unroll
  for (int i = 0; i < 4; ++i)
    ((uint4*)ldsB)[tid + i * 512] = ((const uint4*)wsQT)[tid + i * 512];

  // stage X tile, converting f32 -> bf16, swizzled into A-frag order:
  // A-frag idx for (m_local, k): ((w*4+kstep)*64 + quad*16 + (m_local&15))*8 + (k&7)
  #pragma unroll
  for (int it = 0; it < 8; ++it) {
    int f    = tid + it * 512;            // float4 index, 4096 total
    int mloc = f >> 5;
    int q4   = f & 31;
    int k0   = q4 * 4;
    float4 x4 = ((const float4*)(Xg + (size_t)(row0 + mloc) * kD))[q4];
    int ks = k0 >> 5, qd = (k0 >> 3) & 3, j = k0 & 7;
    int w = mloc >> 4, m = mloc & 15;
    int idx = ((w * 4 + ks) * 64 + qd * 16 + m) * 8 + j;
    bf16x4 v;
    v[0] = (__bf16)x4.x; v[1] = (__bf16)x4.y; v[2] = (__bf16)x4.z; v[3] = (__bf16)x4.w;
    *(bf16x4*)(&ldsA[idx]) = v;
  }
  __syncthreads();

  const int w    = tid >> 6;     // wave 0..7, owns rows row0 + 16w .. +15
  const int lane = tid & 63;
  const int qd   = lane >> 4;    // quad
  const int cc   = lane & 15;    // C-layout col / B-layout n

  f32x4 acc[8];
  #pragma unroll
  for (int nt = 0; nt < 8; ++nt) acc[nt] = (f32x4){0.f, 0.f, 0.f, 0.f};

  // GEMM1: Y[m][e] = sum_d X[m][d] * Q[e][d]
  #pragma unroll
  for (int ks = 0; ks < 4; ++ks) {
    bf16x8 a = *(const bf16x8*)(&ldsA[((w * 4 + ks) * 64 + lane) * 8]);
    #pragma unroll
    for (int nt = 0; nt < 8; ++nt) {
      bf16x8 b = *(const bf16x8*)(&ldsB[((ks * 8 + nt) * 64 + lane) * 8]);
      acc[nt] = __builtin_amdgcn_mfma_f32_16x16x32_bf16(a, b, acc[nt], 0, 0, 0);
    }
  }

  // RoPE in-register. C layout: lane holds (m = qd*4+reg, e = nt*16+cc).
  // Pair (e, e+64) lives in (nt, nt+4) of the SAME lane. cos[e+64] == cos[e].
  const int rowb  = row0 + w * 16;        // within-tensor row of this wave's m=0
  const int bidx  = rowb >> 17;           // / (16*8192)
  const int sbase = rowb & (kS - 1);
  #pragma unroll
  for (int reg = 0; reg < 4; ++reg) {
    int s = sbase + qd * 4 + reg;
    const float* cb = cosg + ((size_t)bidx * kS + s) * kD;
    const float* sb = sing + ((size_t)bidx * kS + s) * kD;
    #pragma unroll
    for (int nt = 0; nt < 4; ++nt) {
      int e = nt * 16 + cc;
      float cv = cb[e];
      float sv = sb[e];
      float ylo = acc[nt][reg];
      float yhi = acc[nt + 4][reg];
      acc[nt][reg]     = ylo * cv - yhi * sv;   // e < 64: rot = -y[e+64]
      acc[nt + 4][reg] = yhi * cv + ylo * sv;   // e >= 64: rot = +y[e-64]
    }
  }

  __syncthreads();  // all waves done reading B-slot (and their A regions)

  // overwrite B-slot with Q frags for GEMM2
  #pragma unroll
  for (int i = 0; i < 4; ++i)
    ((uint4*)ldsB)[tid + i * 512] = ((const uint4*)wsQ)[tid + i * 512];

  // write rotated Y (bf16) into A-slot in A-frag layout (k-dim = e)
  #pragma unroll
  for (int reg = 0; reg < 4; ++reg) {
    int m = qd * 4 + reg;
    #pragma unroll
    for (int nt = 0; nt < 8; ++nt) {
      int e = nt * 16 + cc;
      int ks2 = e >> 5, qd2 = (e >> 3) & 3, j2 = e & 7;
      ldsA[((w * 4 + ks2) * 64 + qd2 * 16 + m) * 8 + j2] = (__bf16)acc[nt][reg];
    }
  }
  __syncthreads();

  // GEMM2: Z[m][e] = sum_d Yr[m][d] * Q[d][e]
  f32x4 acc2[8];
  #pragma unroll
  for (int nt = 0; nt < 8; ++nt) acc2[nt] = (f32x4){0.f, 0.f, 0.f, 0.f};
  #pragma unroll
  for (int ks = 0; ks < 4; ++ks) {
    bf16x8 a = *(const bf16x8*)(&ldsA[((w * 4 + ks) * 64 + lane) * 8]);
    #pragma unroll
    for (int nt = 0; nt < 8; ++nt) {
      bf16x8 b = *(const bf16x8*)(&ldsB[((ks * 8 + nt) * 64 + lane) * 8]);
      acc2[nt] = __builtin_amdgcn_mfma_f32_16x16x32_bf16(a, b, acc2[nt], 0, 0, 0);
    }
  }

  // epilogue: f32 stores
  #pragma unroll
  for (int reg = 0; reg < 4; ++reg) {
    float* orow = Og + (size_t)(rowb + qd * 4 + reg) * kD;
    #pragma unroll
    for (int nt = 0; nt < 8; ++nt)
      orow[nt * 16 + cc] = acc2[nt][reg];
  }
}

extern "C" void kernel_launch(void* const* d_in, const int* in_sizes, int n_in,
                              void* d_out, int out_size, void* d_ws, size_t ws_size,
                              hipStream_t stream) {
  const float* q    = (const float*)d_in[0];
  const float* k    = (const float*)d_in[1];
  const float* vs   = (const float*)d_in[2];
  const float* cosg = (const float*)d_in[3];
  const float* sing = (const float*)d_in[4];
  __bf16* wsQT = (__bf16*)d_ws;
  __bf16* wsQ  = wsQT + kFragElems;

  rnrope_build_q<<<8, 1024, 0, stream>>>(vs, wsQT, wsQ);
  rnrope_main<<<4096, 512, 0, stream>>>(q, k, cosg, sing, wsQT, wsQ, (float*)d_out);
}

// Round 2
// 481.215 us; speedup vs baseline: 1.0086x; 1.0086x over previous
//
#include <hip/hip_runtime.h>

typedef __bf16 bf16x8 __attribute__((ext_vector_type(8)));
typedef __bf16 bf16x4 __attribute__((ext_vector_type(4)));
typedef float  f32x4  __attribute__((ext_vector_type(4)));

static constexpr int kS = 8192;
static constexpr int kD = 128;
static constexpr int kRowsPerTensor = 2 * 16 * kS;            // 262144
static constexpr int kFragElems = 128 * 128;                  // 16384 bf16 per matrix

// ---------------------------------------------------------------------------
// Kernel 1: build Householder product Q, column-parallel (one wave per column).
// Column j evolves independently: w_j = v . Q[:,j]; Q[:,j] -= c * w_j * v.
// Emits Q^T and Q in bf16, pre-swizzled into MFMA B-fragment order:
//   frag idx for element (k, n) = ((kstep*8 + ntile)*64 + quad*16 + (n&15))*8 + (k&7)
// ---------------------------------------------------------------------------
__global__ __launch_bounds__(1024) void rnrope_build_q(
    const float* __restrict__ vs,
    __bf16* __restrict__ wsQT,   // B-operand for GEMM1: B1[k][n] = Q[n][k]
    __bf16* __restrict__ wsQ) {  // B-operand for GEMM2: B2[k][n] = Q[k][n]
  __shared__ float vsh[64 * 128];
  const int tid = threadIdx.x;
  for (int i = tid; i < 2048; i += 1024)
    ((float4*)vsh)[i] = ((const float4*)vs)[i];
  __syncthreads();

  const int col  = blockIdx.x * 16 + (tid >> 6);  // 0..127 (grid = 8 blocks)
  const int lane = tid & 63;

  float qlo = (col == lane)      ? 1.0f : 0.0f;   // Q[lane][col]
  float qhi = (col == lane + 64) ? 1.0f : 0.0f;   // Q[lane+64][col]

  for (int r = 0; r < 64; ++r) {
    float vlo = vsh[r * 128 + lane];
    float vhi = vsh[r * 128 + lane + 64];
    float t0 = vlo * qlo + vhi * qhi;   // partial v . q_col
    float t1 = vlo * vlo + vhi * vhi;   // partial v . v
    #pragma unroll
    for (int off = 32; off > 0; off >>= 1) {
      t0 += __shfl_xor(t0, off);
      t1 += __shfl_xor(t1, off);
    }
    float cf = 2.0f / (t1 + 1e-8f);
    float sf = cf * t0;
    qlo -= sf * vlo;
    qhi -= sf * vhi;
  }

  // Q^T frags: element (k=col, n=i), i = lane, lane+64
  {
    const int ks = col >> 5, qd = (col >> 3) & 3, jj = col & 7;
    #pragma unroll
    for (int h = 0; h < 2; ++h) {
      int i = lane + h * 64;
      float val = h ? qhi : qlo;
      int nt = i >> 4;
      int lp = qd * 16 + (i & 15);
      wsQT[((ks * 8 + nt) * 64 + lp) * 8 + jj] = (__bf16)val;
    }
  }
  // Q frags: element (k=i, n=col)
  {
    const int nt = col >> 4;
    const int nn = col & 15;
    #pragma unroll
    for (int h = 0; h < 2; ++h) {
      int i = lane + h * 64;
      float val = h ? qhi : qlo;
      int ks = i >> 5, qd = (i >> 3) & 3, jj = i & 7;
      wsQ[((ks * 8 + nt) * 64 + qd * 16 + nn) * 8 + jj] = (__bf16)val;
    }
  }
}

// ---------------------------------------------------------------------------
// Kernel 2: per 128-row tile: Y = X @ Q^T (MFMA), RoPE in-register with
// on-the-fly cos/sin (v_exp + v_sin/v_cos; no cos/sin global reads),
// LDS round-trip (C-layout -> A-layout), Z = Yrot @ Q (MFMA),
// then f32 LDS transpose for fully-coalesced float4 stores.
// LDS: one 64 KiB arena; B-slot (16 KiB... 32 KiB) + A-slot (32 KiB),
// reused as a 128x128 f32 tile for the store epilogue.
// ---------------------------------------------------------------------------
__global__ __launch_bounds__(512, 4) void rnrope_main(
    const float* __restrict__ qg, const float* __restrict__ kg,
    const __bf16* __restrict__ wsQT, const __bf16* __restrict__ wsQ,
    float* __restrict__ outg) {
  __shared__ __align__(16) __bf16 lds[2 * kFragElems];   // 64 KiB arena
  __bf16* ldsB = lds;                 // 32 KiB: B frags
  __bf16* ldsA = lds + kFragElems;    // 32 KiB: A frags
  float*  ldsF = (float*)lds;         // 64 KiB: f32 out tile (epilogue)

  const int tid    = threadIdx.x;
  const int blk    = blockIdx.x;          // 0..4095
  const int tensor = blk >> 11;           // 0 = q, 1 = k
  const int tile   = blk & 2047;
  const float* __restrict__ Xg = tensor ? kg : qg;
  float* __restrict__ Og = outg + (size_t)tensor * (size_t)kRowsPerTensor * kD;
  const int row0 = tile * 128;

  // stage Q^T frags into B-slot (already frag-ordered in ws)
  #pragma unroll
  for (int i = 0; i < 4; ++i)
    ((uint4*)ldsB)[tid + i * 512] = ((const uint4*)wsQT)[tid + i * 512];

  // stage X tile, f32 -> bf16, swizzled into A-frag order
  #pragma unroll
  for (int it = 0; it < 8; ++it) {
    int f    = tid + it * 512;            // float4 index, 4096 total
    int mloc = f >> 5;
    int q4   = f & 31;
    int k0   = q4 * 4;
    float4 x4 = ((const float4*)(Xg + (size_t)(row0 + mloc) * kD))[q4];
    int ks = k0 >> 5, qd = (k0 >> 3) & 3, j = k0 & 7;
    int w = mloc >> 4, m = mloc & 15;
    int idx = ((w * 4 + ks) * 64 + qd * 16 + m) * 8 + j;
    bf16x4 v;
    v[0] = (__bf16)x4.x; v[1] = (__bf16)x4.y; v[2] = (__bf16)x4.z; v[3] = (__bf16)x4.w;
    *(bf16x4*)(&ldsA[idx]) = v;
  }
  __syncthreads();

  const int w    = tid >> 6;     // wave 0..7, owns rows row0 + 16w .. +15
  const int lane = tid & 63;
  const int qd   = lane >> 4;    // quad
  const int cc   = lane & 15;    // C-layout col / B-layout n

  f32x4 acc[8];
  #pragma unroll
  for (int nt = 0; nt < 8; ++nt) acc[nt] = (f32x4){0.f, 0.f, 0.f, 0.f};

  // GEMM1: Y[m][e] = sum_d X[m][d] * Q[e][d]
  #pragma unroll
  for (int ks = 0; ks < 4; ++ks) {
    bf16x8 a = *(const bf16x8*)(&ldsA[((w * 4 + ks) * 64 + lane) * 8]);
    #pragma unroll
    for (int nt = 0; nt < 8; ++nt) {
      bf16x8 b = *(const bf16x8*)(&ldsB[((ks * 8 + nt) * 64 + lane) * 8]);
      acc[nt] = __builtin_amdgcn_mfma_f32_16x16x32_bf16(a, b, acc[nt], 0, 0, 0);
    }
  }

  // RoPE in-register, cos/sin computed on the fly.
  // C layout: lane holds (m = qd*4+reg, e = nt*16+cc); pair (e, e+64) lives
  // in (nt, nt+4) of the SAME lane; cos[e+64] == cos[e], freq idx = e (<64).
  // inv_freq[e] = 10000^(-e/64) = exp2(-e * log2(10000)/64)
  const int rowb  = row0 + w * 16;
  const int sbase = rowb & (kS - 1);
  const float kNegL = -0.20762050593046967f;   // -log2(10000)/64
  float invf[4];
  #pragma unroll
  for (int nt = 0; nt < 4; ++nt)
    invf[nt] = exp2f(kNegL * (float)(nt * 16 + cc));
  #pragma unroll
  for (int reg = 0; reg < 4; ++reg) {
    float spos = (float)(sbase + qd * 4 + reg);
    #pragma unroll
    for (int nt = 0; nt < 4; ++nt) {
      float ang = spos * invf[nt];
      float sv, cv;
      __sincosf(ang, &sv, &cv);
      float ylo = acc[nt][reg];
      float yhi = acc[nt + 4][reg];
      acc[nt][reg]     = ylo * cv - yhi * sv;   // e < 64:  rot = -y[e+64]
      acc[nt + 4][reg] = yhi * cv + ylo * sv;   // e >= 64: rot = +y[e-64]
    }
  }

  __syncthreads();  // all waves done reading B-slot / A-slot

  // overwrite B-slot with Q frags for GEMM2
  #pragma unroll
  for (int i = 0; i < 4; ++i)
    ((uint4*)ldsB)[tid + i * 512] = ((const uint4*)wsQ)[tid + i * 512];

  // write rotated Y (bf16) into A-slot in A-frag layout (k-dim = e)
  #pragma unroll
  for (int reg = 0; reg < 4; ++reg) {
    int m = qd * 4 + reg;
    #pragma unroll
    for (int nt = 0; nt < 8; ++nt) {
      int e = nt * 16 + cc;
      int ks2 = e >> 5, qd2 = (e >> 3) & 3, j2 = e & 7;
      ldsA[((w * 4 + ks2) * 64 + qd2 * 16 + m) * 8 + j2] = (__bf16)acc[nt][reg];
    }
  }
  __syncthreads();

  // GEMM2: Z[m][e] = sum_d Yr[m][d] * Q[d][e]  (reuse acc registers)
  #pragma unroll
  for (int nt = 0; nt < 8; ++nt) acc[nt] = (f32x4){0.f, 0.f, 0.f, 0.f};
  #pragma unroll
  for (int ks = 0; ks < 4; ++ks) {
    bf16x8 a = *(const bf16x8*)(&ldsA[((w * 4 + ks) * 64 + lane) * 8]);
    #pragma unroll
    for (int nt = 0; nt < 8; ++nt) {
      bf16x8 b = *(const bf16x8*)(&ldsB[((ks * 8 + nt) * 64 + lane) * 8]);
      acc[nt] = __builtin_amdgcn_mfma_f32_16x16x32_bf16(a, b, acc[nt], 0, 0, 0);
    }
  }

  // epilogue: C-layout -> f32 LDS tile -> fully coalesced float4 stores
  __syncthreads();  // everyone done reading frag slots; reuse arena as f32
  #pragma unroll
  for (int reg = 0; reg < 4; ++reg) {
    int m = w * 16 + qd * 4 + reg;
    #pragma unroll
    for (int nt = 0; nt < 8; ++nt)
      ldsF[m * kD + nt * 16 + cc] = acc[nt][reg];
  }
  __syncthreads();
  float4* __restrict__ Ot = (float4*)(Og + (size_t)row0 * kD);
  #pragma unroll
  for (int it = 0; it < 8; ++it) {
    int idx = tid + it * 512;             // float4 index, 4096 total
    Ot[idx] = ((const float4*)ldsF)[idx];
  }
}

extern "C" void kernel_launch(void* const* d_in, const int* in_sizes, int n_in,
                              void* d_out, int out_size, void* d_ws, size_t ws_size,
                              hipStream_t stream) {
  const float* q    = (const float*)d_in[0];
  const float* k    = (const float*)d_in[1];
  const float* vs   = (const float*)d_in[2];
  __bf16* wsQT = (__bf16*)d_ws;
  __bf16* wsQ  = wsQT + kFragElems;

  rnrope_build_q<<<8, 1024, 0, stream>>>(vs, wsQT, wsQ);
  rnrope_main<<<4096, 512, 0, stream>>>(q, k, wsQT, wsQ, (float*)d_out);
}